// Round 1
// baseline (225.097 us; speedup 1.0000x reference)
//
#include <hip/hip_runtime.h>
#include <math.h>

// Problem constants (fixed by the reference).
namespace {
constexpr int kNH = 8;        // heads
constexpr int kTD = 4;        // transition dim
constexpr int kID = 512;      // input dim
constexpr int kNO = 288;      // outputs/token: 128 (in) + 128 (out) + 32 (eig)
constexpr int kTT = 16;       // tokens per block
constexpr float kFactor = 0.1f;
constexpr float kEps = 1e-3f;
constexpr int kCS = 292;      // LDS C stride (floats), 16B-aligned rows
}

// One-shot weight transpose into [k4][o][4] float4 layout for coalesced loads.
__global__ void transpose_w_kernel(const float* __restrict__ inW,
                                   const float* __restrict__ outW,
                                   const float* __restrict__ eigW,
                                   float4* __restrict__ wt2) {
    int gid = blockIdx.x * 256 + threadIdx.x;   // 128*288 = 36864 float4s
    if (gid >= 128 * kNO) return;
    int o = gid % kNO;
    int k4 = gid / kNO;
    const float* row = (o < 128) ? (inW + (size_t)o * kID)
                     : (o < 256) ? (outW + (size_t)(o - 128) * kID)
                                 : (eigW + (size_t)(o - 256) * kID);
    wt2[gid] = *(const float4*)(row + k4 * 4);
}

template<bool USE_WT>
__global__ __launch_bounds__(320)
void lrt_kernel(const float* __restrict__ x,
                const float* __restrict__ inB,  const float* __restrict__ inW,
                const float* __restrict__ outB, const float* __restrict__ outW,
                const float* __restrict__ eigB, const float* __restrict__ eigW,
                const float4* __restrict__ wt2,
                float* __restrict__ out) {
    __shared__ float C[kTT][kCS];
    const int tid = threadIdx.x;
    const int tok0 = blockIdx.x * kTT;

    // ---------- Phase 1: projection GEMM (fp32 VALU) ----------
    // Thread o in [0,288) computes acc[t] = sum_k W[o][k] * x[tok0+t][k] for 16 tokens.
    if (tid < kNO) {
        const int o = tid;
        float acc[kTT];
        #pragma unroll
        for (int t = 0; t < kTT; ++t) acc[t] = 0.0f;

        const float* xb = x + (size_t)tok0 * kID;
        const float* wrow = nullptr;
        if (!USE_WT) {
            wrow = (o < 128) ? (inW + (size_t)o * kID)
                 : (o < 256) ? (outW + (size_t)(o - 128) * kID)
                             : (eigW + (size_t)(o - 256) * kID);
        }

        for (int k4 = 0; k4 < kID / 4; ++k4) {
            float4 w;
            if (USE_WT) w = wt2[k4 * kNO + o];                 // coalesced across lanes
            else        w = *(const float4*)(wrow + k4 * 4);   // scattered fallback
            #pragma unroll
            for (int t = 0; t < kTT; ++t) {
                // wave-uniform address -> scalar (s_load) path, L1/constant-cached
                float4 xv = *(const float4*)(xb + (size_t)t * kID + k4 * 4);
                acc[t] = fmaf(w.x, xv.x, acc[t]);
                acc[t] = fmaf(w.y, xv.y, acc[t]);
                acc[t] = fmaf(w.z, xv.z, acc[t]);
                acc[t] = fmaf(w.w, xv.w, acc[t]);
            }
        }

        const float bias = (o < 128) ? inB[o]
                         : (o < 256) ? outB[o - 128]
                                     : eigB[o - 256];
        #pragma unroll
        for (int t = 0; t < kTT; ++t) C[t][o] = acc[t] + bias;
    }
    __syncthreads();

    // ---------- Phase 2: ortho_exp on 4x4 matrices ----------
    // 256 items: (token t, head n, side in/out). E = sum_{p=0}^{15} skew^p / p!
    // (reference's normalizer cancels: coeff[p]*sk^p == skew^p/p! exactly).
    if (tid < 256) {
        const int t = tid & 15;
        const int n = (tid >> 4) & 7;
        const int side = tid >> 7;            // 0 = in, 1 = out
        const int o0 = side * 128 + n * 16;

        float M[16];
        #pragma unroll
        for (int i = 0; i < 16; ++i) M[i] = C[t][o0 + i];

        float S[16];
        #pragma unroll
        for (int a = 0; a < 4; ++a)
            #pragma unroll
            for (int b = 0; b < 4; ++b)
                S[a * 4 + b] = kFactor * (M[a * 4 + b] - M[b * 4 + a]);

        // Horner: R = I; for j=15..1: R = I + (S/j) * R
        float R[16];
        #pragma unroll
        for (int i = 0; i < 16; ++i) R[i] = (i % 5 == 0) ? 1.0f : 0.0f;
        #pragma unroll
        for (int j = 15; j >= 1; --j) {
            const float inv = 1.0f / (float)j;   // compile-time constant
            float Rn[16];
            #pragma unroll
            for (int a = 0; a < 4; ++a) {
                #pragma unroll
                for (int c = 0; c < 4; ++c) {
                    float s = S[a * 4 + 0] * R[0 * 4 + c];
                    s = fmaf(S[a * 4 + 1], R[1 * 4 + c], s);
                    s = fmaf(S[a * 4 + 2], R[2 * 4 + c], s);
                    s = fmaf(S[a * 4 + 3], R[3 * 4 + c], s);
                    Rn[a * 4 + c] = s * inv + ((a == c) ? 1.0f : 0.0f);
                }
            }
            #pragma unroll
            for (int i = 0; i < 16; ++i) R[i] = Rn[i];
        }
        // write E back in place (exclusive row segment per thread)
        #pragma unroll
        for (int i = 0; i < 16; ++i) C[t][o0 + i] = R[i];
    }
    __syncthreads();

    // ---------- Phase 3: transition = outE @ diag(tanh(eig)) @ inE ----------
    if (tid < 128) {
        const int t = tid & 15;
        const int n = tid >> 4;

        float IE[16], OE[16], d[4];
        #pragma unroll
        for (int i = 0; i < 16; ++i) IE[i] = C[t][n * 16 + i];
        #pragma unroll
        for (int i = 0; i < 16; ++i) OE[i] = C[t][128 + n * 16 + i];
        #pragma unroll
        for (int b = 0; b < 4; ++b) d[b] = tanhf(C[t][256 + n * 4 + b]);

        // OD[a][b] = OE[a][b] * d[b], then R = OD @ IE
        float R[16];
        #pragma unroll
        for (int a = 0; a < 4; ++a) {
            float od0 = OE[a * 4 + 0] * d[0];
            float od1 = OE[a * 4 + 1] * d[1];
            float od2 = OE[a * 4 + 2] * d[2];
            float od3 = OE[a * 4 + 3] * d[3];
            #pragma unroll
            for (int c = 0; c < 4; ++c) {
                float s = od0 * IE[0 * 4 + c];
                s = fmaf(od1, IE[1 * 4 + c], s);
                s = fmaf(od2, IE[2 * 4 + c], s);
                s = fmaf(od3, IE[3 * 4 + c], s);
                R[a * 4 + c] = s;
            }
        }

        float* op = out + ((size_t)(tok0 + t) * kNH + n) * 16;
        #pragma unroll
        for (int a = 0; a < 4; ++a) {
            float4 v = make_float4(R[a * 4 + 0], R[a * 4 + 1],
                                   R[a * 4 + 2], R[a * 4 + 3]);
            *(float4*)(op + a * 4) = v;
        }
    }
}

extern "C" void kernel_launch(void* const* d_in, const int* in_sizes, int n_in,
                              void* d_out, int out_size, void* d_ws, size_t ws_size,
                              hipStream_t stream) {
    const float* x    = (const float*)d_in[0];
    const float* inB  = (const float*)d_in[1];
    const float* inW  = (const float*)d_in[2];
    const float* outB = (const float*)d_in[3];
    const float* outW = (const float*)d_in[4];
    const float* eigB = (const float*)d_in[5];
    const float* eigW = (const float*)d_in[6];
    float* out = (float*)d_out;

    const int n_tokens = in_sizes[0] / kID;          // B*S = 16384
    const int n_blocks = (n_tokens + kTT - 1) / kTT; // 1024

    const size_t wt_bytes = (size_t)(kID / 4) * kNO * sizeof(float4); // 576 KiB
    if (ws_size >= wt_bytes && d_ws != nullptr) {
        float4* wt2 = (float4*)d_ws;
        transpose_w_kernel<<<(128 * kNO + 255) / 256, 256, 0, stream>>>(inW, outW, eigW, wt2);
        lrt_kernel<true><<<n_blocks, 320, 0, stream>>>(x, inB, inW, outB, outW,
                                                       eigB, eigW, wt2, out);
    } else {
        lrt_kernel<false><<<n_blocks, 320, 0, stream>>>(x, inB, inW, outB, outW,
                                                        eigB, eigW, nullptr, out);
    }
}

// Round 4
// 111.002 us; speedup vs baseline: 2.0279x; 2.0279x over previous
//
#include <hip/hip_runtime.h>
#include <math.h>

typedef __attribute__((ext_vector_type(8))) short short8;
typedef __attribute__((ext_vector_type(16))) float f32x16;

namespace {
constexpr int kID = 512;    // input dim (K)
constexpr int kNO = 288;    // 128 in + 128 out + 32 eig (N)
constexpr int kBM = 64;     // tokens per block (M tile)
constexpr int kNT = 9;      // N tiles of 32
constexpr int kKS = 32;     // k-steps of 16
constexpr int kCS = 296;    // LDS C stride (floats)
constexpr float kFactor = 0.1f;
}

// RNE float -> bf16 (bit pattern), avoids header API differences.
__device__ __forceinline__ unsigned short f2bf(float f) {
    unsigned u = __float_as_uint(f);
    unsigned r = 0x7fffu + ((u >> 16) & 1u);
    return (unsigned short)((u + r) >> 16);
}

// ---------- Prep: W -> bf16 in MFMA B-fragment order ----------
// Fragment (kstep, nt, lane) holds W[n = nt*32 + (lane&31)][k = kstep*16 + (lane>>5)*8 + j], j=0..7.
__global__ void prep_w(const float* __restrict__ inW, const float* __restrict__ outW,
                       const float* __restrict__ eigW, unsigned short* __restrict__ wws) {
    int gid = blockIdx.x * 256 + threadIdx.x;      // [0, 32*9*64)
    if (gid >= kKS * kNT * 64) return;
    int lane  = gid & 63;
    int nt    = (gid >> 6) % kNT;
    int kstep = gid / (64 * kNT);
    int n = nt * 32 + (lane & 31);
    int k = kstep * 16 + (lane >> 5) * 8;
    const float* src = (n < 128 ? inW + (size_t)n * kID
                       : n < 256 ? outW + (size_t)(n - 128) * kID
                                 : eigW + (size_t)(n - 256) * kID) + k;
    unsigned short* dst = wws + (size_t)gid * 8;
    #pragma unroll
    for (int j = 0; j < 8; ++j) dst[j] = f2bf(src[j]);
}

// ---------- Main: MFMA GEMM (no LDS in K-loop) + fused epilogue ----------
__global__ __launch_bounds__(384)
void lrt_main(const float* __restrict__ x, const unsigned short* __restrict__ wws,
              const float* __restrict__ inB, const float* __restrict__ outB,
              const float* __restrict__ eigB, float* __restrict__ out) {
    __shared__ float Cld[32 * kCS];   // 37888 B, one 32-token half at a time
    __shared__ float sB[kNO];

    const int tid  = threadIdx.x;
    const int tok0 = blockIdx.x * kBM;

    if (tid < kNO)
        sB[tid] = tid < 128 ? inB[tid] : tid < 256 ? outB[tid - 128] : eigB[tid - 256];

    const int w    = tid >> 6;
    const int lane = tid & 63;
    const int mt   = w & 1;       // M tile (32 tokens)
    const int ng   = w >> 1;      // N group: tiles ng*3 .. ng*3+2
    const int row  = mt * 32 + (lane & 31);
    const int h    = lane >> 5;

    f32x16 acc0, acc1, acc2;
    #pragma unroll
    for (int i = 0; i < 16; ++i) { acc0[i] = 0.f; acc1[i] = 0.f; acc2[i] = 0.f; }

    const float* xrow = x + (size_t)(tok0 + row) * kID + h * 8;
    const uint4* wp = (const uint4*)wws;
    const int bcol = ng * 3;

    #pragma unroll 4
    for (int ks = 0; ks < kKS; ++ks) {
        // A fragment: 8 fp32 -> 8 bf16 (k = ks*16 + h*8 + j)
        float4 a0 = *(const float4*)(xrow + ks * 16);
        float4 a1 = *(const float4*)(xrow + ks * 16 + 4);
        short8 a;
        a[0] = (short)f2bf(a0.x); a[1] = (short)f2bf(a0.y);
        a[2] = (short)f2bf(a0.z); a[3] = (short)f2bf(a0.w);
        a[4] = (short)f2bf(a1.x); a[5] = (short)f2bf(a1.y);
        a[6] = (short)f2bf(a1.z); a[7] = (short)f2bf(a1.w);

        uint4 b0 = wp[(size_t)((ks * kNT + bcol + 0) * 64 + lane)];
        uint4 b1 = wp[(size_t)((ks * kNT + bcol + 1) * 64 + lane)];
        uint4 b2 = wp[(size_t)((ks * kNT + bcol + 2) * 64 + lane)];

        acc0 = __builtin_amdgcn_mfma_f32_32x32x16_bf16(a, __builtin_bit_cast(short8, b0), acc0, 0, 0, 0);
        acc1 = __builtin_amdgcn_mfma_f32_32x32x16_bf16(a, __builtin_bit_cast(short8, b1), acc1, 0, 0, 0);
        acc2 = __builtin_amdgcn_mfma_f32_32x32x16_bf16(a, __builtin_bit_cast(short8, b2), acc2, 0, 0, 0);
    }

    // ---------- Epilogue: two 32-token halves through LDS ----------
    for (int hf = 0; hf < 2; ++hf) {
        __syncthreads();   // C region free (prev half's reads done / bias written)
        if (mt == hf) {
            #pragma unroll
            for (int i = 0; i < 3; ++i) {
                const f32x16& A = (i == 0) ? acc0 : (i == 1) ? acc1 : acc2;
                const int col = (bcol + i) * 32 + (lane & 31);
                #pragma unroll
                for (int rg = 0; rg < 16; ++rg) {
                    int trow = (rg & 3) + 8 * (rg >> 2) + 4 * h;  // D: row=(reg&3)+8*(reg>>2)+4*(lane>>5)
                    Cld[trow * kCS + col] = A[rg];
                }
            }
        }
        __syncthreads();
        if (tid < 256) {
            const int t = tid >> 3, head = tid & 7;
            const float* cr = &Cld[t * kCS];

            float Min[16], Mout[16], d[4];
            #pragma unroll
            for (int i = 0; i < 16; ++i) Min[i]  = cr[head * 16 + i]       + sB[head * 16 + i];
            #pragma unroll
            for (int i = 0; i < 16; ++i) Mout[i] = cr[128 + head * 16 + i] + sB[128 + head * 16 + i];
            #pragma unroll
            for (int b = 0; b < 4; ++b)  d[b] = tanhf(cr[256 + head * 4 + b] + sB[256 + head * 4 + b]);

            // ortho_exp: E = sum_{p=0}^{15} skew^p / p!  (normalizer cancels analytically)
            float Ein[16], Eout[16];
            #pragma unroll
            for (int side = 0; side < 2; ++side) {
                const float* M = side ? Mout : Min;
                float S[16];
                #pragma unroll
                for (int a = 0; a < 4; ++a)
                    #pragma unroll
                    for (int b = 0; b < 4; ++b)
                        S[a * 4 + b] = kFactor * (M[a * 4 + b] - M[b * 4 + a]);
                float R[16];
                #pragma unroll
                for (int i = 0; i < 16; ++i) R[i] = (i % 5 == 0) ? 1.0f : 0.0f;
                #pragma unroll
                for (int j = 15; j >= 1; --j) {
                    const float inv = 1.0f / (float)j;
                    float Rn[16];
                    #pragma unroll
                    for (int a = 0; a < 4; ++a)
                        #pragma unroll
                        for (int c = 0; c < 4; ++c) {
                            float s = S[a * 4 + 0] * R[0 * 4 + c];
                            s = fmaf(S[a * 4 + 1], R[1 * 4 + c], s);
                            s = fmaf(S[a * 4 + 2], R[2 * 4 + c], s);
                            s = fmaf(S[a * 4 + 3], R[3 * 4 + c], s);
                            Rn[a * 4 + c] = s * inv + ((a == c) ? 1.0f : 0.0f);
                        }
                    #pragma unroll
                    for (int i = 0; i < 16; ++i) R[i] = Rn[i];
                }
                float* E = side ? Eout : Ein;
                #pragma unroll
                for (int i = 0; i < 16; ++i) E[i] = R[i];
            }

            // transition = Eout * diag(d) * Ein
            float R[16];
            #pragma unroll
            for (int a = 0; a < 4; ++a) {
                float od0 = Eout[a * 4 + 0] * d[0];
                float od1 = Eout[a * 4 + 1] * d[1];
                float od2 = Eout[a * 4 + 2] * d[2];
                float od3 = Eout[a * 4 + 3] * d[3];
                #pragma unroll
                for (int c = 0; c < 4; ++c) {
                    float s = od0 * Ein[0 * 4 + c];
                    s = fmaf(od1, Ein[1 * 4 + c], s);
                    s = fmaf(od2, Ein[2 * 4 + c], s);
                    s = fmaf(od3, Ein[3 * 4 + c], s);
                    R[a * 4 + c] = s;
                }
            }

            float* op = out + ((size_t)(tok0 + hf * 32 + t) * 8 + head) * 16;
            #pragma unroll
            for (int a = 0; a < 4; ++a)
                *(float4*)(op + a * 4) = make_float4(R[a * 4 + 0], R[a * 4 + 1],
                                                     R[a * 4 + 2], R[a * 4 + 3]);
        }
    }
}

extern "C" void kernel_launch(void* const* d_in, const int* in_sizes, int n_in,
                              void* d_out, int out_size, void* d_ws, size_t ws_size,
                              hipStream_t stream) {
    const float* x    = (const float*)d_in[0];
    const float* inB  = (const float*)d_in[1];
    const float* inW  = (const float*)d_in[2];
    const float* outB = (const float*)d_in[3];
    const float* outW = (const float*)d_in[4];
    const float* eigB = (const float*)d_in[5];
    const float* eigW = (const float*)d_in[6];
    float* out = (float*)d_out;

    unsigned short* wws = (unsigned short*)d_ws;   // 32*9*64*16 B = 288 KiB

    const int n_tokens = in_sizes[0] / kID;        // 16384
    const int n_blocks = n_tokens / kBM;           // 256

    prep_w<<<(kKS * kNT * 64 + 255) / 256, 256, 0, stream>>>(inW, outW, eigW, wws);
    lrt_main<<<n_blocks, 384, 0, stream>>>(x, wws, inB, outB, eigB, out);
}

// Round 10
// 100.698 us; speedup vs baseline: 2.2354x; 1.1023x over previous
//
#include <hip/hip_runtime.h>
#include <math.h>

typedef __attribute__((ext_vector_type(8))) short short8;
typedef __attribute__((ext_vector_type(16))) float f32x16;

namespace {
constexpr int kID = 512;    // input dim (K)
constexpr int kNO = 288;    // 128 in + 128 out + 32 eig (N)
constexpr int kBM = 32;     // tokens per block (M tile)
constexpr int kNT = 9;      // N tiles of 32
constexpr int kKS = 32;     // k-steps of 16
constexpr int kCS = 296;    // LDS C stride (floats)
constexpr float kFactor = 0.1f;
constexpr int kABytes = kKS * 1024;        // A-fragment region: 32 KiB
constexpr int kCBytes = kBM * kCS * 4;     // C tile: 37888 B (aliases A)
constexpr int kSmem   = kCBytes + kNO * 4; // + bias array
}

// RNE float -> bf16 (bit pattern).
__device__ __forceinline__ unsigned short f2bf(float f) {
    unsigned u = __float_as_uint(f);
    unsigned r = 0x7fffu + ((u >> 16) & 1u);
    return (unsigned short)((u + r) >> 16);
}

// ---------- Prep: W -> bf16 in MFMA B-fragment order ----------
// Fragment (kstep, nt, lane) holds W[n = nt*32 + (lane&31)][k = kstep*16 + (lane>>5)*8 + j], j=0..7.
__global__ void prep_w(const float* __restrict__ inW, const float* __restrict__ outW,
                       const float* __restrict__ eigW, unsigned short* __restrict__ wws) {
    int gid = blockIdx.x * 256 + threadIdx.x;      // [0, 32*9*64)
    if (gid >= kKS * kNT * 64) return;
    int lane  = gid & 63;
    int nt    = (gid >> 6) % kNT;
    int kstep = gid / (64 * kNT);
    int n = nt * 32 + (lane & 31);
    int k = kstep * 16 + (lane >> 5) * 8;
    const float* src = (n < 128 ? inW + (size_t)n * kID
                       : n < 256 ? outW + (size_t)(n - 128) * kID
                                 : eigW + (size_t)(n - 256) * kID) + k;
    unsigned short* dst = wws + (size_t)gid * 8;
    #pragma unroll
    for (int j = 0; j < 8; ++j) dst[j] = f2bf(src[j]);
}

// ---------- Main: staged-A MFMA GEMM + fused epilogue ----------
// 9 waves: wave w computes the 32-token x 32-col tile w. 2 blocks/CU target.
__global__ __launch_bounds__(576, 5)
void lrt_main(const float* __restrict__ x, const unsigned short* __restrict__ wws,
              const float* __restrict__ inB, const float* __restrict__ outB,
              const float* __restrict__ eigB, float* __restrict__ out) {
    __shared__ __align__(16) char smem[kSmem];
    char*  Ash = smem;                     // bf16 A fragments (phase 0/1)
    float* Cld = (float*)smem;             // fp32 C tile (phase 2+), aliases Ash
    float* sB  = (float*)(smem + kCBytes); // biases [288]

    const int tid  = threadIdx.x;
    const int tok0 = blockIdx.x * kBM;

    if (tid < kNO)
        sB[tid] = tid < 128 ? inB[tid] : tid < 256 ? outB[tid - 128] : eigB[tid - 256];

    // ---- Phase 0: stage x tile (32x512 fp32) as bf16 A-fragments in LDS ----
    // Job (t, k8): load 8 floats x[t][k8*8..+8], cvt, one ds_write_b128.
    // Fragment layout: byte = ks*1024 + (t + 32*h)*16, XOR-swizzled by (ks&7)<<4.
    for (int j = tid; j < kBM * 64; j += 576) {
        const int t  = j >> 6;
        const int k8 = j & 63;
        const float* src = x + (size_t)(tok0 + t) * kID + k8 * 8;
        float4 v0 = *(const float4*)(src);
        float4 v1 = *(const float4*)(src + 4);
        short8 a;
        a[0] = (short)f2bf(v0.x); a[1] = (short)f2bf(v0.y);
        a[2] = (short)f2bf(v0.z); a[3] = (short)f2bf(v0.w);
        a[4] = (short)f2bf(v1.x); a[5] = (short)f2bf(v1.y);
        a[6] = (short)f2bf(v1.z); a[7] = (short)f2bf(v1.w);
        const int ks = k8 >> 1, h = k8 & 1;
        int byte = ks * 1024 + (t + 32 * h) * 16;
        byte ^= (ks & 7) << 4;
        *(short8*)(Ash + byte) = a;
    }
    __syncthreads();

    // ---- Phase 1: K-loop. 1 ds_read_b128 + 1 L2 uint4 + 1 MFMA per k-step ----
    const int wv   = tid >> 6;    // N tile index 0..8
    const int lane = tid & 63;
    f32x16 acc;
    #pragma unroll
    for (int i = 0; i < 16; ++i) acc[i] = 0.f;

    const uint4* wp = (const uint4*)wws;
    #pragma unroll 8
    for (int ks = 0; ks < kKS; ++ks) {
        int byte = (ks * 1024 + lane * 16) ^ ((ks & 7) << 4);
        short8 a = *(const short8*)(Ash + byte);
        uint4  b = wp[(size_t)((ks * kNT + wv) * 64 + lane)];
        acc = __builtin_amdgcn_mfma_f32_32x32x16_bf16(a, __builtin_bit_cast(short8, b), acc, 0, 0, 0);
    }
    __syncthreads();   // all A reads done; Cld may now overwrite Ash

    // ---- Phase 2: spill C tile to LDS ----
    {
        const int col = wv * 32 + (lane & 31);
        const int h   = lane >> 5;
        #pragma unroll
        for (int rg = 0; rg < 16; ++rg) {
            int trow = (rg & 3) + 8 * (rg >> 2) + 4 * h;  // D: row=(reg&3)+8*(reg>>2)+4*(lane>>5)
            Cld[trow * kCS + col] = acc[rg];
        }
    }
    __syncthreads();

    // ---- Phase 3: ortho_exp, 512 jobs (token t, head, side) ----
    // E = sum_{p=0}^{15} skew^p / p!  (reference normalizer cancels analytically).
    if (tid < 512) {
        const int side = tid & 1, head = (tid >> 1) & 7, t = tid >> 4;
        float* cr = Cld + t * kCS + side * 128 + head * 16;
        const float* bb = sB + side * 128 + head * 16;

        float M[16];
        #pragma unroll
        for (int c = 0; c < 4; ++c) {
            float4 v = *(const float4*)(cr + c * 4);
            M[c * 4 + 0] = v.x + bb[c * 4 + 0];
            M[c * 4 + 1] = v.y + bb[c * 4 + 1];
            M[c * 4 + 2] = v.z + bb[c * 4 + 2];
            M[c * 4 + 3] = v.w + bb[c * 4 + 3];
        }
        float S[16];
        #pragma unroll
        for (int a = 0; a < 4; ++a)
            #pragma unroll
            for (int b = 0; b < 4; ++b)
                S[a * 4 + b] = kFactor * (M[a * 4 + b] - M[b * 4 + a]);

        float R[16];
        #pragma unroll
        for (int i = 0; i < 16; ++i) R[i] = (i % 5 == 0) ? 1.0f : 0.0f;
        #pragma unroll
        for (int j = 15; j >= 1; --j) {
            const float inv = 1.0f / (float)j;
            float Rn[16];
            #pragma unroll
            for (int a = 0; a < 4; ++a)
                #pragma unroll
                for (int c = 0; c < 4; ++c) {
                    float s = S[a * 4 + 0] * R[0 * 4 + c];
                    s = fmaf(S[a * 4 + 1], R[1 * 4 + c], s);
                    s = fmaf(S[a * 4 + 2], R[2 * 4 + c], s);
                    s = fmaf(S[a * 4 + 3], R[3 * 4 + c], s);
                    Rn[a * 4 + c] = s * inv + ((a == c) ? 1.0f : 0.0f);
                }
            #pragma unroll
            for (int i = 0; i < 16; ++i) R[i] = Rn[i];
        }
        #pragma unroll
        for (int c = 0; c < 4; ++c)
            *(float4*)(cr + c * 4) = make_float4(R[c * 4 + 0], R[c * 4 + 1],
                                                 R[c * 4 + 2], R[c * 4 + 3]);
    }
    __syncthreads();

    // ---- Phase 4: transition = Eout * diag(tanh(eig)) * Ein, 256 jobs ----
    if (tid < 256) {
        const int t = tid >> 3, head = tid & 7;
        const float* cr = Cld + t * kCS;

        float Ein[16], Eout[16], d[4];
        #pragma unroll
        for (int i = 0; i < 16; ++i) Ein[i]  = cr[head * 16 + i];
        #pragma unroll
        for (int i = 0; i < 16; ++i) Eout[i] = cr[128 + head * 16 + i];
        #pragma unroll
        for (int b = 0; b < 4; ++b)
            d[b] = tanhf(cr[256 + head * 4 + b] + sB[256 + head * 4 + b]);

        float R[16];
        #pragma unroll
        for (int a = 0; a < 4; ++a) {
            float od0 = Eout[a * 4 + 0] * d[0];
            float od1 = Eout[a * 4 + 1] * d[1];
            float od2 = Eout[a * 4 + 2] * d[2];
            float od3 = Eout[a * 4 + 3] * d[3];
            #pragma unroll
            for (int c = 0; c < 4; ++c) {
                float s = od0 * Ein[0 * 4 + c];
                s = fmaf(od1, Ein[1 * 4 + c], s);
                s = fmaf(od2, Ein[2 * 4 + c], s);
                s = fmaf(od3, Ein[3 * 4 + c], s);
                R[a * 4 + c] = s;
            }
        }

        float* op = out + ((size_t)(tok0 + t) * 8 + head) * 16;
        #pragma unroll
        for (int a = 0; a < 4; ++a)
            *(float4*)(op + a * 4) = make_float4(R[a * 4 + 0], R[a * 4 + 1],
                                                 R[a * 4 + 2], R[a * 4 + 3]);
    }
}

extern "C" void kernel_launch(void* const* d_in, const int* in_sizes, int n_in,
                              void* d_out, int out_size, void* d_ws, size_t ws_size,
                              hipStream_t stream) {
    const float* x    = (const float*)d_in[0];
    const float* inB  = (const float*)d_in[1];
    const float* inW  = (const float*)d_in[2];
    const float* outB = (const float*)d_in[3];
    const float* outW = (const float*)d_in[4];
    const float* eigB = (const float*)d_in[5];
    const float* eigW = (const float*)d_in[6];
    float* out = (float*)d_out;

    unsigned short* wws = (unsigned short*)d_ws;   // 32*9*64*16 B = 288 KiB

    const int n_tokens = in_sizes[0] / kID;        // 16384
    const int n_blocks = n_tokens / kBM;           // 512

    prep_w<<<(kKS * kNT * 64 + 255) / 256, 256, 0, stream>>>(inW, outW, eigW, wws);
    lrt_main<<<n_blocks, 576, 0, stream>>>(x, wws, inB, outB, eigB, out);
}